// Round 1
// baseline (1723.784 us; speedup 1.0000x reference)
//
#include <hip/hip_runtime.h>
#include <math.h>

// Problem constants
#define BB   64
#define SS   512
#define NHH  4
#define DD   256
#define HH   256
#define LDW  260   // padded LDS row stride (floats) for 64x256 tiles

// ---------------------------------------------------------------------------
// ws layout (floats):
//   [0,256)    v2[h]  = W2 @ (Wq @ w2)
//   [256,512)  cb[h'] = bproj @ W1b
//   [512]      c2     = b2.v + bq.w2
//   [768,1024) qw[b*4+i] carried scalar state (init = bq.w2)
//   [1024,66560) relu_u at t=511 (256 rows x 256)
//   [66560, ...) chunk buffers: kw_c[Tc*256], xw1_c[Tc*65536], kpw_c[Tc*65536]
// ---------------------------------------------------------------------------

__global__ __launch_bounds__(256) void setup_kernel(
    const float* __restrict__ Wq, const float* __restrict__ bq,
    const float* __restrict__ w_mlp, const float* __restrict__ bproj,
    const float* __restrict__ W1, const float* __restrict__ W2,
    const float* __restrict__ b2, float* __restrict__ ws)
{
  __shared__ float vsh[256];
  __shared__ float red[256];
  int tid = threadIdx.x;
  const float* w2 = w_mlp + HH;
  // v[h] = sum_k Wq[h][k] * w2[k]
  float a = 0.f;
  for (int k = 0; k < 256; ++k) a = fmaf(Wq[tid * 256 + k], w2[k], a);
  vsh[tid] = a;
  __syncthreads();
  // v2[h] = sum_k W2[h][k] * v[k]
  float a2 = 0.f;
  for (int k = 0; k < 256; ++k) a2 = fmaf(W2[tid * 256 + k], vsh[k], a2);
  ws[tid] = a2;
  // cb[h'] = sum_k bproj[k] * W1b[k][h']
  float a3 = 0.f;
  for (int k = 0; k < 256; ++k) a3 = fmaf(bproj[k], W1[(256 + k) * 256 + tid], a3);
  ws[256 + tid] = a3;
  // c = bq . w2
  red[tid] = bq[tid] * w2[tid];
  __syncthreads();
  for (int s = 128; s; s >>= 1) { if (tid < s) red[tid] += red[tid + s]; __syncthreads(); }
  float c = red[0];
  __syncthreads();
  ws[768 + tid] = c;              // qw init for all 256 (b,i) rows
  // c2 = b2.v + c
  red[tid] = b2[tid] * vsh[tid];
  __syncthreads();
  for (int s = 128; s; s >>= 1) { if (tid < s) red[tid] += red[tid + s]; __syncthreads(); }
  if (tid == 0) ws[512] = red[0] + c;
}

// ---------------------------------------------------------------------------
// 64-row x 256-col fp32 GEMM from an LDS tile against a global 256x256 weight.
// Lane tile: 4 rows (rb + i*16) x 16 cols (cbase..cbase+15).
// ---------------------------------------------------------------------------
__device__ __forceinline__ void gemm64(const float* __restrict__ W, const float* S,
                                       const float* __restrict__ bias,
                                       float acc[4][16], int rb, int cbase)
{
#pragma unroll
  for (int i = 0; i < 4; ++i)
#pragma unroll
    for (int j = 0; j < 16; ++j)
      acc[i][j] = bias ? bias[cbase + j] : 0.0f;

  for (int k4 = 0; k4 < 64; ++k4) {
    float4 xv[4];
#pragma unroll
    for (int i = 0; i < 4; ++i)
      xv[i] = *(const float4*)&S[(rb + i * 16) * LDW + k4 * 4];
#pragma unroll
    for (int kk = 0; kk < 4; ++kk) {
      float wv[16];
      const float4* wr = (const float4*)&W[((k4 * 4 + kk) << 8) + cbase];
      *(float4*)&wv[0]  = wr[0];
      *(float4*)&wv[4]  = wr[1];
      *(float4*)&wv[8]  = wr[2];
      *(float4*)&wv[12] = wr[3];
#pragma unroll
      for (int i = 0; i < 4; ++i) {
        float xs = ((const float*)(&xv[i]))[kk];
#pragma unroll
        for (int j = 0; j < 16; ++j) acc[i][j] = fmaf(xs, wv[j], acc[i][j]);
      }
    }
  }
}

__device__ __forceinline__ void acc_store_lds(float* D, const float acc[4][16],
                                              int rb, int cbase)
{
#pragma unroll
  for (int i = 0; i < 4; ++i)
#pragma unroll
    for (int j4 = 0; j4 < 4; ++j4)
      *(float4*)&D[(rb + i * 16) * LDW + cbase + j4 * 4] =
          make_float4(acc[i][j4 * 4 + 0], acc[i][j4 * 4 + 1],
                      acc[i][j4 * 4 + 2], acc[i][j4 * 4 + 3]);
}

// copy 64x256 LDS tile to global with row mapping r -> (tc = ttbase + r/4, head = r%4)
// global layout: [tc][b][head][256]
__device__ __forceinline__ void lds_to_global(const float* Ssrc, float* __restrict__ g,
                                              int b, int ttbase)
{
  int tid = threadIdx.x;
#pragma unroll
  for (int i = 0; i < 16; ++i) {
    int f4 = i * 256 + tid;       // float4 index over 64x256 tile
    int r = f4 >> 6;
    int col4 = f4 & 63;
    int tc = ttbase + (r >> 2);
    int head = r & 3;
    float4 v = *(const float4*)&Ssrc[r * LDW + col4 * 4];
    ((float4*)g)[((size_t)(tc * 64 + b) * 4 + head) * 64 + col4] = v;
  }
}

__global__ __launch_bounds__(256) void precompute_kernel(
    const float* __restrict__ x, const float* __restrict__ Wk,
    const float* __restrict__ bk, const float* __restrict__ w_mlp,
    const float* __restrict__ Wproj, const float* __restrict__ W1,
    const float* __restrict__ b1,
    float* __restrict__ kw_c, float* __restrict__ xw1_c, float* __restrict__ kpw_c,
    int t0)
{
  __shared__ float XS[64 * LDW];
  __shared__ float TS[64 * LDW];
  __shared__ float kwbuf[64 * 16];

  int b   = blockIdx.x;   // batch
  int tt  = blockIdx.y;   // 16-timestep block within chunk
  int tid = threadIdx.x;
  int l = tid & 63, w = tid >> 6;
  int rb = l & 15, lg = l >> 4;
  int cbase = (w * 4 + lg) * 16;

  // stage X tile: rows (b, t0+tt*16 .. +16, head 0..3) are contiguous in x
  const float* xsrc = x + (size_t)(b * SS + t0 + tt * 16) * NHH * DD;
#pragma unroll
  for (int i = 0; i < 16; ++i) {
    int f4 = i * 256 + tid;
    int r = f4 >> 6;
    int col4 = f4 & 63;
    *(float4*)&XS[r * LDW + col4 * 4] = ((const float4*)xsrc)[f4];
  }
  __syncthreads();

  float acc[4][16];

  // GEMM A: kx = X @ Wk + bk  -> TS ; also kw = kx . w1
  gemm64(Wk, XS, bk, acc, rb, cbase);
  acc_store_lds(TS, acc, rb, cbase);
  {
    float w1v[16];
    *(float4*)&w1v[0]  = *(const float4*)&w_mlp[cbase + 0];
    *(float4*)&w1v[4]  = *(const float4*)&w_mlp[cbase + 4];
    *(float4*)&w1v[8]  = *(const float4*)&w_mlp[cbase + 8];
    *(float4*)&w1v[12] = *(const float4*)&w_mlp[cbase + 12];
#pragma unroll
    for (int i = 0; i < 4; ++i) {
      float p = 0.f;
#pragma unroll
      for (int j = 0; j < 16; ++j) p = fmaf(acc[i][j], w1v[j], p);
      kwbuf[(rb + i * 16) * 16 + (w * 4 + lg)] = p;
    }
  }
  __syncthreads();
  if (tid < 64) {
    float s = 0.f;
#pragma unroll
    for (int q = 0; q < 16; ++q) s += kwbuf[tid * 16 + q];
    int tc = tt * 16 + (tid >> 2);
    int head = tid & 3;
    kw_c[(size_t)(tc * 64 + b) * 4 + head] = s;
  }

  // GEMM B: xw1 = X @ W1a + b1 -> global
  gemm64(W1, XS, b1, acc, rb, cbase);
  __syncthreads();                   // all reads of XS done
  acc_store_lds(XS, acc, rb, cbase); // overwrite X with xw1
  __syncthreads();
  lds_to_global(XS, xw1_c, b, tt * 16);

  // GEMM C: kp = kx(TS) @ Wproj -> XS
  gemm64(Wproj, TS, nullptr, acc, rb, cbase);
  __syncthreads();                   // xw1 copy reads of XS done
  acc_store_lds(XS, acc, rb, cbase);
  __syncthreads();

  // GEMM D: kpw = kp(XS) @ W1b -> TS -> global
  gemm64(W1 + 256 * 256, XS, nullptr, acc, rb, cbase);
  acc_store_lds(TS, acc, rb, cbase); // TS reads finished before earlier barriers
  __syncthreads();
  lds_to_global(TS, kpw_c, b, tt * 16);
}

// ---------------------------------------------------------------------------
// Sequential scan over a chunk of timesteps. One block per batch b; wave w = head i.
// Carried state: qw scalar per (b,i) in ws[768+...].
// ---------------------------------------------------------------------------
__global__ __launch_bounds__(256) void seq_kernel(
    const float* __restrict__ xw1_c, const float* __restrict__ kpw_c,
    const float* __restrict__ kw_c, float* __restrict__ ws,
    float* __restrict__ relu_u, int t0, int tc_n)
{
  __shared__ float v2s[256];
  __shared__ float cbs[256];
  int b = blockIdx.x;
  int tid = threadIdx.x;
  int i = tid >> 6;
  int l = tid & 63;
  v2s[tid] = ws[tid];
  cbs[tid] = ws[256 + tid];
  __syncthreads();
  float c2 = ws[512];
  float qw = ws[768 + b * 4 + i];
  float4 v2v = *(const float4*)&v2s[l * 4];
  float4 cbv = *(const float4*)&cbs[l * 4];

  const float4* xw = (const float4*)xw1_c;
  const float4* kp = (const float4*)kpw_c;

  float4 xv, kv0, kv1, kv2, kv3;
  float kwa, kwb, kwc, kwd;
  auto load = [&](int tc) {
    size_t rb_ = (size_t)(tc * 64 + b) * 4;
    xv  = xw[(rb_ + i) * 64 + l];
    kv0 = kp[(rb_ + 0) * 64 + l];
    kv1 = kp[(rb_ + 1) * 64 + l];
    kv2 = kp[(rb_ + 2) * 64 + l];
    kv3 = kp[(rb_ + 3) * 64 + l];
    const float* kwp = &kw_c[rb_];
    kwa = kwp[0]; kwb = kwp[1]; kwc = kwp[2]; kwd = kwp[3];
  };
  load(0);

  for (int tc = 0; tc < tc_n; ++tc) {
    float4 X = xv, K0 = kv0, K1 = kv1, K2 = kv2, K3 = kv3;
    float w0 = kwa, w1 = kwb, w2 = kwc, w3 = kwd;
    if (tc + 1 < tc_n) load(tc + 1);   // prefetch next step (independent of qw)

    float e0 = tanhf(qw + w0), e1 = tanhf(qw + w1);
    float e2 = tanhf(qw + w2), e3 = tanhf(qw + w3);
    float m = fmaxf(fmaxf(e0, e1), fmaxf(e2, e3));
    float p0 = __expf(e0 - m), p1 = __expf(e1 - m);
    float p2 = __expf(e2 - m), p3 = __expf(e3 - m);
    float inv = 1.0f / (p0 + p1 + p2 + p3);
    p0 *= inv; p1 *= inv; p2 *= inv; p3 *= inv;

    float4 u;
    u.x = X.x + cbv.x + p0 * K0.x + p1 * K1.x + p2 * K2.x + p3 * K3.x;
    u.y = X.y + cbv.y + p0 * K0.y + p1 * K1.y + p2 * K2.y + p3 * K3.y;
    u.z = X.z + cbv.z + p0 * K0.z + p1 * K1.z + p2 * K2.z + p3 * K3.z;
    u.w = X.w + cbv.w + p0 * K0.w + p1 * K1.w + p2 * K2.w + p3 * K3.w;

    float4 r;
    r.x = fmaxf(u.x, 0.f); r.y = fmaxf(u.y, 0.f);
    r.z = fmaxf(u.z, 0.f); r.w = fmaxf(u.w, 0.f);

    float dot = r.x * v2v.x + r.y * v2v.y + r.z * v2v.z + r.w * v2v.w;
#pragma unroll
    for (int off = 32; off; off >>= 1) dot += __shfl_xor(dot, off, 64);
    qw = dot + c2;

    if (t0 + tc == SS - 1) {
      *(float4*)&relu_u[(size_t)(b * 4 + i) * 256 + l * 4] = r;
    }
  }
  if (l == 0) ws[768 + b * 4 + i] = qw;
}

// hidden_final = relu_u @ W2 + b2  -> d_out[192:]
__global__ __launch_bounds__(256) void final_hidden_kernel(
    const float* __restrict__ relu_u, const float* __restrict__ W2,
    const float* __restrict__ b2, float* __restrict__ out)
{
  __shared__ float rs[256];
  int row = blockIdx.x;
  int tid = threadIdx.x;
  rs[tid] = relu_u[(size_t)row * 256 + tid];
  __syncthreads();
  float acc = b2[tid];
  for (int k = 0; k < 256; ++k) acc = fmaf(rs[k], W2[k * 256 + tid], acc);
  out[192 + (size_t)row * 256 + tid] = acc;
}

// logits = hf.reshape(B, 1024) @ Wo + bo ; log_softmax -> d_out[0:192)
__global__ __launch_bounds__(256) void final_logits_kernel(
    const float* __restrict__ hf, const float* __restrict__ Wo,
    const float* __restrict__ bo, float* __restrict__ outp)
{
  __shared__ float r0[256], r1[256], r2[256];
  int b = blockIdx.x;
  int tid = threadIdx.x;
  float a0 = 0.f, a1 = 0.f, a2 = 0.f;
  for (int k = tid; k < 1024; k += 256) {
    float h = hf[(size_t)b * 1024 + k];
    a0 = fmaf(h, Wo[k * 3 + 0], a0);
    a1 = fmaf(h, Wo[k * 3 + 1], a1);
    a2 = fmaf(h, Wo[k * 3 + 2], a2);
  }
  r0[tid] = a0; r1[tid] = a1; r2[tid] = a2;
  __syncthreads();
  for (int s = 128; s; s >>= 1) {
    if (tid < s) { r0[tid] += r0[tid + s]; r1[tid] += r1[tid + s]; r2[tid] += r2[tid + s]; }
    __syncthreads();
  }
  if (tid == 0) {
    float l0 = r0[0] + bo[0], l1 = r1[0] + bo[1], l2 = r2[0] + bo[2];
    float m = fmaxf(l0, fmaxf(l1, l2));
    float lse = m + logf(expf(l0 - m) + expf(l1 - m) + expf(l2 - m));
    outp[b * 3 + 0] = l0 - lse;
    outp[b * 3 + 1] = l1 - lse;
    outp[b * 3 + 2] = l2 - lse;
  }
}

extern "C" void kernel_launch(void* const* d_in, const int* in_sizes, int n_in,
                              void* d_out, int out_size, void* d_ws, size_t ws_size,
                              hipStream_t stream)
{
  const float* x     = (const float*)d_in[0];
  const float* Wk    = (const float*)d_in[1];
  const float* bk    = (const float*)d_in[2];
  const float* Wq    = (const float*)d_in[3];
  const float* bq    = (const float*)d_in[4];
  const float* w_mlp = (const float*)d_in[5];
  const float* Wproj = (const float*)d_in[6];
  const float* bproj = (const float*)d_in[7];
  const float* W1    = (const float*)d_in[8];
  const float* b1    = (const float*)d_in[9];
  const float* W2    = (const float*)d_in[10];
  const float* b2    = (const float*)d_in[11];
  const float* Wo    = (const float*)d_in[12];
  const float* bo    = (const float*)d_in[13];
  float* out = (float*)d_out;
  float* ws  = (float*)d_ws;

  const size_t OFF_QW = 768;
  const size_t OFF_RU = 1024;
  const size_t OFF_CH = 1024 + (size_t)BB * NHH * HH;   // 66560

  // pick chunk size Tc (multiple of 16) fitting in ws; cap at 128 for LLC locality
  long ws_floats = (long)(ws_size / 4);
  long avail = ws_floats - (long)OFF_CH;
  long per_t = 256 + 2 * 65536;        // kw + xw1 + kpw per timestep
  int Tc = 128;
  while (Tc > 16 && (long)Tc * per_t > avail) Tc -= 16;

  float* qw_st = ws + OFF_QW; (void)qw_st;
  float* ru    = ws + OFF_RU;
  float* kw_c  = ws + OFF_CH;
  float* xw1_c = kw_c + (size_t)Tc * 256;
  float* kpw_c = xw1_c + (size_t)Tc * 65536;

  setup_kernel<<<1, 256, 0, stream>>>(Wq, bq, w_mlp, bproj, W1, W2, b2, ws);

  for (int t0 = 0; t0 < SS; t0 += Tc) {
    int n = SS - t0; if (n > Tc) n = Tc;
    precompute_kernel<<<dim3(BB, n / 16), 256, 0, stream>>>(
        x, Wk, bk, w_mlp, Wproj, W1, b1, kw_c, xw1_c, kpw_c, t0);
    seq_kernel<<<BB, 256, 0, stream>>>(xw1_c, kpw_c, kw_c, ws, ru, t0, n);
  }

  final_hidden_kernel<<<BB * NHH, 256, 0, stream>>>(ru, W2, b2, out);
  final_logits_kernel<<<BB, 256, 0, stream>>>(out + 192, Wo, bo, out);
}

// Round 2
// 690.567 us; speedup vs baseline: 2.4962x; 2.4962x over previous
//
#include <hip/hip_runtime.h>
#include <hip/hip_bf16.h>
#include <math.h>

#define BB   64
#define SS   512
#define NHH  4
#define DD   256
#define HH   256

// bf16 LDS tile: 64 rows x 264 halfwords (256 + 8 pad -> row stride 528B = 16B-aligned)
#define LDH  264

typedef __attribute__((ext_vector_type(8))) short  short8;
typedef __attribute__((ext_vector_type(4))) float  floatx4;

// ---------------------------------------------------------------------------
// ws layout (floats):
//   [0,256)        v2[h]  = W2 @ (Wq @ w2)
//   [256,512)      cb[h'] = bproj @ W1b
//   [512]          c2     = b2.v + bq.w2
//   [768,1024)     qw[b*4+i] carried scalar state
//   [1024,66560)   relu_u at t=511 (256 rows x 256)
//   [66560,197632) packed bf16 weights: 4 mats x 65536 bf16 (Wk, W1a, Wproj, W1b)
//   [197632,...)   chunk buffers (kw Tc*256 | xw1 Tc*65536 | kpw Tc*65536) x1 or x2
// ---------------------------------------------------------------------------

__device__ __forceinline__ unsigned short f2b(float f) {
  __hip_bfloat16 h = __float2bfloat16(f);
  return __builtin_bit_cast(unsigned short, h);
}

// ---------------------------------------------------------------------------
__global__ __launch_bounds__(256) void setup_kernel(
    const float* __restrict__ Wq, const float* __restrict__ bq,
    const float* __restrict__ w_mlp, const float* __restrict__ bproj,
    const float* __restrict__ W1, const float* __restrict__ W2,
    const float* __restrict__ b2, float* __restrict__ ws)
{
  __shared__ float vsh[256];
  __shared__ float red[256];
  int tid = threadIdx.x;
  const float* w2 = w_mlp + HH;
  float a = 0.f;
  for (int k = 0; k < 256; ++k) a = fmaf(Wq[tid * 256 + k], w2[k], a);
  vsh[tid] = a;
  __syncthreads();
  float a2 = 0.f;
  for (int k = 0; k < 256; ++k) a2 = fmaf(W2[tid * 256 + k], vsh[k], a2);
  ws[tid] = a2;
  float a3 = 0.f;
  for (int k = 0; k < 256; ++k) a3 = fmaf(bproj[k], W1[(256 + k) * 256 + tid], a3);
  ws[256 + tid] = a3;
  red[tid] = bq[tid] * w2[tid];
  __syncthreads();
  for (int s = 128; s; s >>= 1) { if (tid < s) red[tid] += red[tid + s]; __syncthreads(); }
  float c = red[0];
  __syncthreads();
  ws[768 + tid] = c;
  red[tid] = b2[tid] * vsh[tid];
  __syncthreads();
  for (int s = 128; s; s >>= 1) { if (tid < s) red[tid] += red[tid + s]; __syncthreads(); }
  if (tid == 0) ws[512] = red[0] + c;
}

// ---------------------------------------------------------------------------
// Pack weights into MFMA B-fragment order (bf16):
// wpack[mat][panel(16)][ks(8)][lane(64)][j(8)] = W[ks*32 + (lane>>4)*8 + j][panel*16 + (lane&15)]
// mats: 0=Wk, 1=W1a, 2=Wproj, 3=W1b
// ---------------------------------------------------------------------------
__global__ __launch_bounds__(256) void pack_weights_kernel(
    const float* __restrict__ Wk, const float* __restrict__ Wproj,
    const float* __restrict__ W1, unsigned short* __restrict__ wpack)
{
  int idx = blockIdx.x * 256 + threadIdx.x;   // 0..262143
  int mat = idx >> 16;
  int rem = idx & 65535;
  int j    = rem & 7;
  int lane = (rem >> 3) & 63;
  int ks   = (rem >> 9) & 7;
  int pan  = rem >> 12;
  int k = ks * 32 + ((lane >> 4) << 3) + j;
  int n = pan * 16 + (lane & 15);
  float v;
  if      (mat == 0) v = Wk[k * 256 + n];
  else if (mat == 1) v = W1[k * 256 + n];
  else if (mat == 2) v = Wproj[k * 256 + n];
  else               v = W1[(256 + k) * 256 + n];
  wpack[idx] = f2b(v);
}

// ---------------------------------------------------------------------------
// One 64x256 (K=256) bf16 MFMA GEMM: A from LDS tile, B from packed global.
// wave w owns rows [w*16, w*16+16); 16 n-tiles of 16x16; acc = 16 x floatx4.
// ---------------------------------------------------------------------------
__device__ __forceinline__ void mfma_gemm(
    const unsigned short* A_lds, const short8* __restrict__ Bp,
    const float* __restrict__ bias, floatx4 acc[16], int l, int w)
{
  int col = l & 15, quad = l >> 4;
  int m = w * 16 + col;
#pragma unroll
  for (int t = 0; t < 16; ++t) {
    float bv = bias ? bias[t * 16 + col] : 0.f;
    acc[t] = (floatx4){bv, bv, bv, bv};
  }
  const short8* Arow = (const short8*)(A_lds + m * LDH + quad * 8);
#pragma unroll
  for (int kb = 0; kb < 8; ++kb) {
    short8 a = Arow[kb * 4];          // 32 halfwords per kb
#pragma unroll
    for (int t = 0; t < 16; ++t) {
      short8 bf = Bp[(t * 8 + kb) * 64 + l];
      acc[t] = __builtin_amdgcn_mfma_f32_16x16x32_bf16(a, bf, acc[t], 0, 0, 0);
    }
  }
}

// acc -> bf16 LDS tile (row-local per wave, no barrier needed)
__device__ __forceinline__ void acc_to_lds_bf16(
    unsigned short* D, const floatx4 acc[16], int l, int w)
{
  int col = l & 15, quad = l >> 4;
#pragma unroll
  for (int t = 0; t < 16; ++t)
#pragma unroll
    for (int r = 0; r < 4; ++r) {
      int m2 = w * 16 + quad * 4 + r;
      D[m2 * LDH + t * 16 + col] = f2b(acc[t][r]);
    }
}

// acc -> global fp32, layout [tc][b][head][256]
__device__ __forceinline__ void acc_to_global(
    float* __restrict__ dst, const floatx4 acc[16], int l, int w, int b, int tt)
{
  int col = l & 15, quad = l >> 4;
  size_t gidx[4];
#pragma unroll
  for (int r = 0; r < 4; ++r) {
    int m2 = w * 16 + quad * 4 + r;
    gidx[r] = (((size_t)(tt * 16 + (m2 >> 2)) * 64 + b) * 4 + (m2 & 3)) * 256;
  }
#pragma unroll
  for (int t = 0; t < 16; ++t)
#pragma unroll
    for (int r = 0; r < 4; ++r)
      dst[gidx[r] + t * 16 + col] = acc[t][r];
}

// ---------------------------------------------------------------------------
__device__ void precompute_block(
    int px, const float* __restrict__ x, const unsigned short* __restrict__ wpack,
    const float* __restrict__ bk, const float* __restrict__ b1,
    const float* __restrict__ w_mlp,
    float* __restrict__ kw_c, float* __restrict__ xw1_c, float* __restrict__ kpw_c,
    int t0, char* smem)
{
  float* kwbuf = (float*)smem;                                // 64x16 fp32
  unsigned short* XS = (unsigned short*)(smem + 4096);        // 64xLDH bf16
  unsigned short* TS = (unsigned short*)(smem + 4096 + 64 * LDH * 2);

  int b  = px & 63;
  int tt = px >> 6;
  int tid = threadIdx.x;
  int l = tid & 63, w = tid >> 6;
  int col = l & 15, quad = l >> 4;

  // stage X (64x256 fp32 -> bf16 LDS), coalesced
  const float4* xsrc = (const float4*)(x + (size_t)(b * SS + t0 + tt * 16) * NHH * DD);
#pragma unroll
  for (int i = 0; i < 16; ++i) {
    int f4 = i * 256 + tid;
    int r = f4 >> 6, c4 = f4 & 63;
    float4 v = xsrc[f4];
    ushort4 h;
    h.x = f2b(v.x); h.y = f2b(v.y); h.z = f2b(v.z); h.w = f2b(v.w);
    *(ushort4*)&XS[r * LDH + c4 * 4] = h;
  }
  __syncthreads();

  const short8* wp0 = (const short8*)(wpack);                 // Wk
  const short8* wp1 = (const short8*)(wpack + 65536);         // W1a
  const short8* wp2 = (const short8*)(wpack + 2 * 65536);    // Wproj
  const short8* wp3 = (const short8*)(wpack + 3 * 65536);    // W1b

  floatx4 acc[16];

  // GEMM A: kx = X@Wk + bk  -> TS (bf16) ; kw partials -> kwbuf
  mfma_gemm(XS, wp0, bk, acc, l, w);
  {
    float s[4] = {0.f, 0.f, 0.f, 0.f};
#pragma unroll
    for (int t = 0; t < 16; ++t) {
      float w1v = w_mlp[t * 16 + col];
#pragma unroll
      for (int r = 0; r < 4; ++r) {
        int m2 = w * 16 + quad * 4 + r;
        TS[m2 * LDH + t * 16 + col] = f2b(acc[t][r]);
        s[r] = fmaf(acc[t][r], w1v, s[r]);
      }
    }
#pragma unroll
    for (int r = 0; r < 4; ++r)
      kwbuf[(w * 16 + quad * 4 + r) * 16 + col] = s[r];
  }
  __syncthreads();
  if (tid < 64) {
    float s = 0.f;
#pragma unroll
    for (int q = 0; q < 16; ++q) s += kwbuf[tid * 16 + q];
    kw_c[((size_t)(tt * 16 + (tid >> 2)) * 64 + b) * 4 + (tid & 3)] = s;
  }

  // GEMM B: xw1 = X@W1a + b1 -> global
  mfma_gemm(XS, wp1, b1, acc, l, w);
  acc_to_global(xw1_c, acc, l, w, b, tt);

  // GEMM C: kp = kx@Wproj -> XS (bf16); XS reads (GEMM B A-frags) done in-wave
  mfma_gemm(TS, wp2, nullptr, acc, l, w);
  acc_to_lds_bf16(XS, acc, l, w);

  // GEMM D: kpw = kp@W1b -> global
  mfma_gemm(XS, wp3, nullptr, acc, l, w);
  acc_to_global(kpw_c, acc, l, w, b, tt);
}

// ---------------------------------------------------------------------------
// DPP wave64 sum-reduce; returns total (broadcast via readlane 63)
// ---------------------------------------------------------------------------
__device__ __forceinline__ float wave_reduce_sum(float x) {
#define DPPSTEP(ctrl, rmask)                                                   \
  {                                                                            \
    int _s = __builtin_amdgcn_update_dpp(0, __builtin_bit_cast(int, x),        \
                                         (ctrl), (rmask), 0xf, true);          \
    x += __builtin_bit_cast(float, _s);                                        \
  }
  DPPSTEP(0x111, 0xf)   // row_shr:1
  DPPSTEP(0x112, 0xf)   // row_shr:2
  DPPSTEP(0x114, 0xf)   // row_shr:4
  DPPSTEP(0x118, 0xf)   // row_shr:8
  DPPSTEP(0x142, 0xa)   // row_bcast15 -> rows 1,3
  DPPSTEP(0x143, 0xc)   // row_bcast31 -> rows 2,3
#undef DPPSTEP
  return __builtin_bit_cast(float, __builtin_amdgcn_readlane(__builtin_bit_cast(int, x), 63));
}

__device__ __forceinline__ float tanh_fast(float y) {
  float ex = __expf(2.f * y);
  return 1.f - 2.f * __builtin_amdgcn_rcpf(ex + 1.f);
}

// ---------------------------------------------------------------------------
__device__ void seq_block(
    const float* __restrict__ xw1_c, const float* __restrict__ kpw_c,
    const float* __restrict__ kw_c, float* __restrict__ ws,
    float* __restrict__ relu_u, int t0, int n)
{
  int b = blockIdx.x;
  int tid = threadIdx.x;
  int i = tid >> 6, l = tid & 63;

  float4 v2v = ((const float4*)ws)[l];
  float4 cbv = ((const float4*)(ws + 256))[l];
  float c2 = ws[512];
  float qw = ws[768 + b * 4 + i];

  const float4* xw = (const float4*)xw1_c;
  const float4* kp = (const float4*)kpw_c;

  struct Slot { float4 x, k0, k1, k2, k3, kw; };

  auto load = [&](Slot& s, int tc) {
    size_t rb_ = (size_t)(tc * 64 + b) * 4;
    float4 xv = xw[(rb_ + i) * 64 + l];
    s.x.x = xv.x + cbv.x; s.x.y = xv.y + cbv.y;
    s.x.z = xv.z + cbv.z; s.x.w = xv.w + cbv.w;
    s.k0 = kp[(rb_ + 0) * 64 + l];
    s.k1 = kp[(rb_ + 1) * 64 + l];
    s.k2 = kp[(rb_ + 2) * 64 + l];
    s.k3 = kp[(rb_ + 3) * 64 + l];
    s.kw = *(const float4*)&kw_c[rb_];
  };

  auto step = [&](Slot& s, int t) {
    float e0 = tanh_fast(qw + s.kw.x);
    float e1 = tanh_fast(qw + s.kw.y);
    float e2 = tanh_fast(qw + s.kw.z);
    float e3 = tanh_fast(qw + s.kw.w);
    float q0 = __expf(e0), q1 = __expf(e1), q2 = __expf(e2), q3 = __expf(e3);
    float inv = __builtin_amdgcn_rcpf(q0 + q1 + q2 + q3);
    float4 a;
    a.x = fmaf(q0, s.k0.x, fmaf(q1, s.k1.x, fmaf(q2, s.k2.x, q3 * s.k3.x)));
    a.y = fmaf(q0, s.k0.y, fmaf(q1, s.k1.y, fmaf(q2, s.k2.y, q3 * s.k3.y)));
    a.z = fmaf(q0, s.k0.z, fmaf(q1, s.k1.z, fmaf(q2, s.k2.z, q3 * s.k3.z)));
    a.w = fmaf(q0, s.k0.w, fmaf(q1, s.k1.w, fmaf(q2, s.k2.w, q3 * s.k3.w)));
    float4 u;
    u.x = fmaf(a.x, inv, s.x.x); u.y = fmaf(a.y, inv, s.x.y);
    u.z = fmaf(a.z, inv, s.x.z); u.w = fmaf(a.w, inv, s.x.w);
    float4 r;
    r.x = fmaxf(u.x, 0.f); r.y = fmaxf(u.y, 0.f);
    r.z = fmaxf(u.z, 0.f); r.w = fmaxf(u.w, 0.f);
    float d = fmaf(r.x, v2v.x, fmaf(r.y, v2v.y, fmaf(r.z, v2v.z, r.w * v2v.w)));
    qw = wave_reduce_sum(d) + c2;
    if (t0 + t == SS - 1)
      *(float4*)&relu_u[(size_t)(b * 4 + i) * 256 + l * 4] = r;
  };

  Slot s0, s1, s2, s3;
  load(s0, 0); load(s1, 1); load(s2, 2); load(s3, 3);
  for (int t = 0; t < n; t += 4) {
    int nt;
    step(s0, t);     nt = t + 4; load(s0, nt < n ? nt : n - 1);
    step(s1, t + 1); nt = t + 5; load(s1, nt < n ? nt : n - 1);
    step(s2, t + 2); nt = t + 6; load(s2, nt < n ? nt : n - 1);
    step(s3, t + 3); nt = t + 7; load(s3, nt < n ? nt : n - 1);
  }
  if (l == 0) ws[768 + b * 4 + i] = qw;
}

// ---------------------------------------------------------------------------
// Fused launch: blocks [0,64) = seq chunk (bufA), blocks [64,..) = precompute (bufB)
// ---------------------------------------------------------------------------
__global__ __launch_bounds__(256, 2) void fused_kernel(
    const float* __restrict__ x, const unsigned short* __restrict__ wpack,
    const float* __restrict__ bk, const float* __restrict__ b1,
    const float* __restrict__ w_mlp,
    float* kwB, float* xw1B, float* kpwB, int t0_pre,
    const float* kwA, const float* xw1A, const float* kpwA, int t0_seq, int n_seq,
    float* __restrict__ ws, float* __restrict__ relu_u)
{
  __shared__ __align__(16) char smem[4096 + 2 * 64 * LDH * 2];
  if (blockIdx.x < 64) {
    if (n_seq > 0) seq_block(xw1A, kpwA, kwA, ws, relu_u, t0_seq, n_seq);
    return;
  }
  precompute_block(blockIdx.x - 64, x, wpack, bk, b1, w_mlp,
                   kwB, xw1B, kpwB, t0_pre, smem);
}

// ---------------------------------------------------------------------------
__global__ __launch_bounds__(256) void final_hidden_kernel(
    const float* __restrict__ relu_u, const float* __restrict__ W2,
    const float* __restrict__ b2, float* __restrict__ out)
{
  __shared__ float rs[256];
  int row = blockIdx.x;
  int tid = threadIdx.x;
  rs[tid] = relu_u[(size_t)row * 256 + tid];
  __syncthreads();
  float acc = b2[tid];
  for (int k = 0; k < 256; ++k) acc = fmaf(rs[k], W2[k * 256 + tid], acc);
  out[192 + (size_t)row * 256 + tid] = acc;
}

__global__ __launch_bounds__(256) void final_logits_kernel(
    const float* __restrict__ hf, const float* __restrict__ Wo,
    const float* __restrict__ bo, float* __restrict__ outp)
{
  __shared__ float r0[256], r1[256], r2[256];
  int b = blockIdx.x;
  int tid = threadIdx.x;
  float a0 = 0.f, a1 = 0.f, a2 = 0.f;
  for (int k = tid; k < 1024; k += 256) {
    float h = hf[(size_t)b * 1024 + k];
    a0 = fmaf(h, Wo[k * 3 + 0], a0);
    a1 = fmaf(h, Wo[k * 3 + 1], a1);
    a2 = fmaf(h, Wo[k * 3 + 2], a2);
  }
  r0[tid] = a0; r1[tid] = a1; r2[tid] = a2;
  __syncthreads();
  for (int s = 128; s; s >>= 1) {
    if (tid < s) { r0[tid] += r0[tid + s]; r1[tid] += r1[tid + s]; r2[tid] += r2[tid + s]; }
    __syncthreads();
  }
  if (tid == 0) {
    float l0 = r0[0] + bo[0], l1 = r1[0] + bo[1], l2 = r2[0] + bo[2];
    float m = fmaxf(l0, fmaxf(l1, l2));
    float lse = m + logf(expf(l0 - m) + expf(l1 - m) + expf(l2 - m));
    outp[b * 3 + 0] = l0 - lse;
    outp[b * 3 + 1] = l1 - lse;
    outp[b * 3 + 2] = l2 - lse;
  }
}

// ---------------------------------------------------------------------------
extern "C" void kernel_launch(void* const* d_in, const int* in_sizes, int n_in,
                              void* d_out, int out_size, void* d_ws, size_t ws_size,
                              hipStream_t stream)
{
  const float* x     = (const float*)d_in[0];
  const float* Wk    = (const float*)d_in[1];
  const float* bk    = (const float*)d_in[2];
  const float* Wq    = (const float*)d_in[3];
  const float* bq    = (const float*)d_in[4];
  const float* w_mlp = (const float*)d_in[5];
  const float* Wproj = (const float*)d_in[6];
  const float* bproj = (const float*)d_in[7];
  const float* W1    = (const float*)d_in[8];
  const float* b1    = (const float*)d_in[9];
  const float* W2    = (const float*)d_in[10];
  const float* b2    = (const float*)d_in[11];
  const float* Wo    = (const float*)d_in[12];
  const float* bo    = (const float*)d_in[13];
  float* out = (float*)d_out;
  float* ws  = (float*)d_ws;

  float* ru = ws + 1024;
  unsigned short* wpack = (unsigned short*)(ws + 66560);
  const size_t OFF_CH = 66560 + 131072;            // 197632 floats
  const long per_t = 256 + 2 * 65536;              // 131328 floats per timestep

  long ws_floats = (long)(ws_size / 4);
  long avail = ws_floats - (long)OFF_CH;

  int Tc = 128;
  while (Tc > 0 && 2L * Tc * per_t > avail) Tc -= 16;
  bool pipelined = (Tc >= 16);
  if (!pipelined) {
    Tc = 128;
    while (Tc > 16 && (long)Tc * per_t > avail) Tc -= 16;
  }

  float* bufA = ws + OFF_CH;
  float* bufB = pipelined ? bufA + (size_t)Tc * per_t : bufA;

  auto kw_of  = [&](float* base) { return base; };
  auto xw_of  = [&](float* base) { return base + (size_t)Tc * 256; };
  auto kpw_of = [&](float* base) { return base + (size_t)Tc * 256 + (size_t)Tc * 65536; };

  pack_weights_kernel<<<1024, 256, 0, stream>>>(Wk, Wproj, W1, wpack);
  setup_kernel<<<1, 256, 0, stream>>>(Wq, bq, w_mlp, bproj, W1, W2, b2, ws);

  int C = (SS + Tc - 1) / Tc;

  if (pipelined) {
    for (int r = 0; r <= C; ++r) {
      bool hasPre = (r < C);
      bool hasSeq = (r >= 1);
      int t0p = r * Tc;
      int np  = hasPre ? ((SS - t0p) < Tc ? (SS - t0p) : Tc) : 0;
      int t0s = (r - 1) * Tc;
      int ns  = hasSeq ? ((SS - t0s) < Tc ? (SS - t0s) : Tc) : 0;
      float* pB = ((r & 1) ? bufB : bufA);
      float* pA = (((r - 1) & 1) ? bufB : bufA);
      int grid = 64 + (hasPre ? 64 * (np / 16) : 0);
      fused_kernel<<<grid, 256, 0, stream>>>(
          x, wpack, bk, b1, w_mlp,
          kw_of(pB), xw_of(pB), kpw_of(pB), t0p,
          kw_of(pA), xw_of(pA), kpw_of(pA), t0s, ns,
          ws, ru);
    }
  } else {
    for (int c = 0; c < C; ++c) {
      int t0 = c * Tc;
      int n = (SS - t0) < Tc ? (SS - t0) : Tc;
      // precompute-only
      fused_kernel<<<64 + 64 * (n / 16), 256, 0, stream>>>(
          x, wpack, bk, b1, w_mlp,
          kw_of(bufA), xw_of(bufA), kpw_of(bufA), t0,
          kw_of(bufA), xw_of(bufA), kpw_of(bufA), 0, 0,
          ws, ru);
      // seq-only
      fused_kernel<<<64, 256, 0, stream>>>(
          x, wpack, bk, b1, w_mlp,
          kw_of(bufA), xw_of(bufA), kpw_of(bufA), t0,
          kw_of(bufA), xw_of(bufA), kpw_of(bufA), t0, n,
          ws, ru);
    }
  }

  final_hidden_kernel<<<BB * NHH, 256, 0, stream>>>(ru, W2, b2, out);
  final_logits_kernel<<<BB, 256, 0, stream>>>(out + 192, Wo, bo, out);
}

// Round 3
// 427.823 us; speedup vs baseline: 4.0292x; 1.6141x over previous
//
#include <hip/hip_runtime.h>
#include <hip/hip_bf16.h>
#include <math.h>

#define BB   64
#define SS   512
#define NHH  4
#define DD   256
#define HH   256
#define LDH  264   // bf16 LDS row stride (halfwords)

typedef __attribute__((ext_vector_type(8))) short  short8;
typedef __attribute__((ext_vector_type(4))) float  floatx4;

// ---------------------------------------------------------------------------
// ws layout (floats):
//   [0,256)        v2[h]  = W2 @ (Wq @ w2)
//   [256,512)      cb[h'] = bproj @ W1b
//   [512]          c2     = b2.v + bq.w2
//   [768,1024)     qw[b*4+i] carried scalar state
//   [1024,66560)   relu_u at t=511 (256 rows x 256) fp32
//   [66560,197632) packed bf16 weights: 4 mats x 65536 bf16 (Wk, W1a, Wproj, W1b)
//   [197632,...)   chunk buffers x2: kw Tc*256 fp32 | xw1 Tc*65536 bf16 | kpw Tc*65536 bf16
// ---------------------------------------------------------------------------

__device__ __forceinline__ unsigned short f2b(float f) {
  __hip_bfloat16 h = __float2bfloat16(f);
  return __builtin_bit_cast(unsigned short, h);
}
__device__ __forceinline__ float b2f(unsigned short u) {
  unsigned v = (unsigned)u << 16;
  return __builtin_bit_cast(float, v);
}

// ---------------------------------------------------------------------------
// init: block 0 = setup scalars/vectors; blocks 1..1024 = weight packing
// wpack[mat][panel(16)][ks(8)][lane(64)][j(8)] = W[ks*32+(lane>>4)*8+j][panel*16+(lane&15)]
// ---------------------------------------------------------------------------
__global__ __launch_bounds__(256) void init_kernel(
    const float* __restrict__ Wk, const float* __restrict__ Wproj,
    const float* __restrict__ W1, const float* __restrict__ Wq,
    const float* __restrict__ bq, const float* __restrict__ w_mlp,
    const float* __restrict__ bproj, const float* __restrict__ W2,
    const float* __restrict__ b2, float* __restrict__ ws,
    unsigned short* __restrict__ wpack)
{
  __shared__ float vsh[256];
  __shared__ float red[256];
  int tid = threadIdx.x;

  if (blockIdx.x > 0) {
    int idx = (blockIdx.x - 1) * 256 + tid;   // 0..262143
    int mat = idx >> 16;
    int rem = idx & 65535;
    int j    = rem & 7;
    int lane = (rem >> 3) & 63;
    int ks   = (rem >> 9) & 7;
    int pan  = rem >> 12;
    int k = ks * 32 + ((lane >> 4) << 3) + j;
    int n = pan * 16 + (lane & 15);
    float v;
    if      (mat == 0) v = Wk[k * 256 + n];
    else if (mat == 1) v = W1[k * 256 + n];
    else if (mat == 2) v = Wproj[k * 256 + n];
    else               v = W1[(256 + k) * 256 + n];
    wpack[idx] = f2b(v);
    return;
  }

  const float* w2 = w_mlp + HH;
  // v[h] = Wq[h,:] . w2
  {
    float a = 0.f;
    const float4* Wq4 = (const float4*)(Wq + tid * 256);
    const float4* w24 = (const float4*)w2;
    for (int k = 0; k < 64; ++k) {
      float4 wv = Wq4[k], xv = w24[k];
      a = fmaf(wv.x, xv.x, fmaf(wv.y, xv.y, fmaf(wv.z, xv.z, fmaf(wv.w, xv.w, a))));
    }
    vsh[tid] = a;
  }
  __syncthreads();
  // v2[h] = W2[h,:] . v
  {
    float a2 = 0.f;
    const float4* W24 = (const float4*)(W2 + tid * 256);
    const float4* v4  = (const float4*)vsh;
    for (int k = 0; k < 64; ++k) {
      float4 wv = W24[k], xv = v4[k];
      a2 = fmaf(wv.x, xv.x, fmaf(wv.y, xv.y, fmaf(wv.z, xv.z, fmaf(wv.w, xv.w, a2))));
    }
    ws[tid] = a2;
  }
  // cb[h'] = bproj . W1b[:,h']   (coalesced over tid)
  {
    float a3 = 0.f;
    for (int k = 0; k < 256; ++k) a3 = fmaf(bproj[k], W1[(256 + k) * 256 + tid], a3);
    ws[256 + tid] = a3;
  }
  // c = bq . w2
  red[tid] = bq[tid] * w2[tid];
  __syncthreads();
  for (int s = 128; s; s >>= 1) { if (tid < s) red[tid] += red[tid + s]; __syncthreads(); }
  float c = red[0];
  __syncthreads();
  ws[768 + tid] = c;                 // qw init for all 256 (b,i) chains
  // c2 = b2.v + c
  red[tid] = b2[tid] * vsh[tid];
  __syncthreads();
  for (int s = 128; s; s >>= 1) { if (tid < s) red[tid] += red[tid + s]; __syncthreads(); }
  if (tid == 0) ws[512] = red[0] + c;
}

// ---------------------------------------------------------------------------
// 64x256 (K=256) bf16 MFMA GEMM, 4x B-reuse: wave w owns n-panels [w*4,w*4+4),
// loops all 4 m-fragments from LDS. acc[mf][pp]. Depth-2 B / depth-1 A prefetch.
// ---------------------------------------------------------------------------
__device__ __forceinline__ void mfma_gemm4(
    const unsigned short* A_lds, const short8* __restrict__ Bp,
    const float* __restrict__ bias, floatx4 acc[4][4], int l, int w)
{
  int col = l & 15, quad = l >> 4;
#pragma unroll
  for (int pp = 0; pp < 4; ++pp) {
    float bv = bias ? bias[(w * 4 + pp) * 16 + col] : 0.f;
#pragma unroll
    for (int mf = 0; mf < 4; ++mf)
      acc[mf][pp] = (floatx4){bv, bv, bv, bv};
  }
  const short8* Bb = Bp + (size_t)(w * 4) * 512 + l;   // panel stride = 8*64 short8
  short8 bb[3][4];
  short8 aa[2][4];
#pragma unroll
  for (int pp = 0; pp < 4; ++pp) bb[0][pp] = Bb[pp * 512];
#pragma unroll
  for (int pp = 0; pp < 4; ++pp) bb[1][pp] = Bb[pp * 512 + 64];
#pragma unroll
  for (int mf = 0; mf < 4; ++mf)
    aa[0][mf] = *(const short8*)(A_lds + (mf * 16 + col) * LDH + quad * 8);
#pragma unroll
  for (int kb = 0; kb < 8; ++kb) {
    if (kb + 2 < 8) {
#pragma unroll
      for (int pp = 0; pp < 4; ++pp)
        bb[(kb + 2) % 3][pp] = Bb[pp * 512 + (kb + 2) * 64];
    }
    if (kb + 1 < 8) {
#pragma unroll
      for (int mf = 0; mf < 4; ++mf)
        aa[(kb + 1) & 1][mf] =
            *(const short8*)(A_lds + (mf * 16 + col) * LDH + (kb + 1) * 32 + quad * 8);
    }
#pragma unroll
    for (int mf = 0; mf < 4; ++mf)
#pragma unroll
      for (int pp = 0; pp < 4; ++pp)
        acc[mf][pp] = __builtin_amdgcn_mfma_f32_16x16x32_bf16(
            aa[kb & 1][mf], bb[kb % 3][pp], acc[mf][pp], 0, 0, 0);
  }
}

// acc -> bf16 LDS tile (all rows, wave's 64 cols)
__device__ __forceinline__ void acc_to_lds(
    unsigned short* D, const floatx4 acc[4][4], int l, int w)
{
  int col = l & 15, quad = l >> 4;
#pragma unroll
  for (int mf = 0; mf < 4; ++mf)
#pragma unroll
    for (int pp = 0; pp < 4; ++pp)
#pragma unroll
      for (int r = 0; r < 4; ++r)
        D[(mf * 16 + quad * 4 + r) * LDH + (w * 4 + pp) * 16 + col] = f2b(acc[mf][pp][r]);
}

// acc -> global bf16, layout [tc][b][head][256]
__device__ __forceinline__ void acc_to_global(
    unsigned short* __restrict__ dst, const floatx4 acc[4][4],
    int l, int w, int b, int tt)
{
  int col = l & 15, quad = l >> 4;
#pragma unroll
  for (int mf = 0; mf < 4; ++mf)
#pragma unroll
    for (int r = 0; r < 4; ++r) {
      int m2 = mf * 16 + quad * 4 + r;
      size_t base = (((size_t)(tt * 16 + (m2 >> 2)) * 64 + b) * 4 + (m2 & 3)) * 256;
#pragma unroll
      for (int pp = 0; pp < 4; ++pp)
        dst[base + (w * 4 + pp) * 16 + col] = f2b(acc[mf][pp][r]);
    }
}

// ---------------------------------------------------------------------------
__device__ void precompute_block(
    int px, const float* __restrict__ x, const unsigned short* __restrict__ wpack,
    const float* __restrict__ bk, const float* __restrict__ b1,
    const float* __restrict__ w_mlp,
    float* __restrict__ kw_c, unsigned short* __restrict__ xw1_c,
    unsigned short* __restrict__ kpw_c, int t0, char* smem)
{
  float* kwbuf = (float*)smem;                              // [64][4] fp32
  unsigned short* XS = (unsigned short*)(smem + 2048);
  unsigned short* TS = XS + 64 * LDH;

  int b  = px & 63;
  int tt = px >> 6;
  int tid = threadIdx.x;
  int l = tid & 63, w = tid >> 6;
  int col = l & 15, quad = l >> 4;

  // stage X (64x256 fp32 -> bf16 LDS), coalesced
  const float4* xsrc = (const float4*)(x + (size_t)(b * SS + t0 + tt * 16) * NHH * DD);
#pragma unroll
  for (int i = 0; i < 16; ++i) {
    int f4 = i * 256 + tid;
    int r = f4 >> 6, c4 = f4 & 63;
    float4 v = xsrc[f4];
    ushort4 h;
    h.x = f2b(v.x); h.y = f2b(v.y); h.z = f2b(v.z); h.w = f2b(v.w);
    *(ushort4*)&XS[r * LDH + c4 * 4] = h;
  }
  __syncthreads();

  const short8* wp0 = (const short8*)(wpack);               // Wk
  const short8* wp1 = (const short8*)(wpack + 65536);       // W1a
  const short8* wp2 = (const short8*)(wpack + 2 * 65536);   // Wproj
  const short8* wp3 = (const short8*)(wpack + 3 * 65536);   // W1b

  floatx4 acc[4][4];

  // GEMM A: kx = X@Wk + bk -> TS (bf16)
  mfma_gemm4(XS, wp0, bk, acc, l, w);
  acc_to_lds(TS, acc, l, w);
  __syncthreads();

  // kw partials: wave w covers cols [w*64, w*64+64), row = l
  {
    float part = 0.f;
    const unsigned short* trow = TS + l * LDH + w * 64;
#pragma unroll
    for (int j8 = 0; j8 < 8; ++j8) {
      short8 tv = *(const short8*)(trow + j8 * 8);
#pragma unroll
      for (int j = 0; j < 8; ++j)
        part = fmaf(b2f((unsigned short)tv[j]), w_mlp[w * 64 + j8 * 8 + j], part);
    }
    kwbuf[l * 4 + w] = part;
  }

  // GEMM B: xw1 = X@W1a + b1 (reads XS)
  mfma_gemm4(XS, wp1, b1, acc, l, w);
  __syncthreads();   // kwbuf complete + all XS reads done
  if (tid < 64) {
    float s = kwbuf[tid * 4] + kwbuf[tid * 4 + 1] + kwbuf[tid * 4 + 2] + kwbuf[tid * 4 + 3];
    kw_c[((size_t)(tt * 16 + (tid >> 2)) * 64 + b) * 4 + (tid & 3)] = s;
  }
  acc_to_global(xw1_c, acc, l, w, b, tt);

  // GEMM C: kp = kx(TS)@Wproj -> XS (bf16)
  mfma_gemm4(TS, wp2, nullptr, acc, l, w);
  acc_to_lds(XS, acc, l, w);
  __syncthreads();

  // GEMM D: kpw = kp(XS)@W1b -> global bf16
  mfma_gemm4(XS, wp3, nullptr, acc, l, w);
  acc_to_global(kpw_c, acc, l, w, b, tt);
}

// ---------------------------------------------------------------------------
__device__ __forceinline__ float wave_reduce_sum(float x) {
#define DPPSTEP(ctrl, rmask)                                                   \
  {                                                                            \
    int _s = __builtin_amdgcn_update_dpp(0, __builtin_bit_cast(int, x),        \
                                         (ctrl), (rmask), 0xf, true);          \
    x += __builtin_bit_cast(float, _s);                                        \
  }
  DPPSTEP(0x111, 0xf)   // row_shr:1
  DPPSTEP(0x112, 0xf)   // row_shr:2
  DPPSTEP(0x114, 0xf)   // row_shr:4
  DPPSTEP(0x118, 0xf)   // row_shr:8
  DPPSTEP(0x142, 0xa)   // row_bcast15
  DPPSTEP(0x143, 0xc)   // row_bcast31
#undef DPPSTEP
  return __builtin_bit_cast(float, __builtin_amdgcn_readlane(__builtin_bit_cast(int, x), 63));
}

__device__ __forceinline__ float tanh_fast(float y) {
  float ex = __expf(2.f * y);
  return 1.f - 2.f * __builtin_amdgcn_rcpf(ex + 1.f);
}

// ---------------------------------------------------------------------------
__device__ void seq_block(
    const unsigned short* __restrict__ xw1_c, const unsigned short* __restrict__ kpw_c,
    const float* __restrict__ kw_c, float* __restrict__ ws,
    float* __restrict__ relu_u, int t0, int n)
{
  int b = blockIdx.x;
  int tid = threadIdx.x;
  int i = tid >> 6, l = tid & 63;

  float4 v2v = ((const float4*)ws)[l];
  float4 cbv = ((const float4*)(ws + 256))[l];
  float c2 = ws[512];
  float qw = ws[768 + b * 4 + i];

  const ushort4* xw = (const ushort4*)xw1_c;
  const ushort4* kp = (const ushort4*)kpw_c;

  struct Slot { ushort4 x, k0, k1, k2, k3; float4 kw; };

  auto load = [&](Slot& s, int tc) {
    size_t rb_ = (size_t)(tc * 64 + b) * 4;
    s.x  = xw[(rb_ + i) * 64 + l];
    s.k0 = kp[(rb_ + 0) * 64 + l];
    s.k1 = kp[(rb_ + 1) * 64 + l];
    s.k2 = kp[(rb_ + 2) * 64 + l];
    s.k3 = kp[(rb_ + 3) * 64 + l];
    s.kw = *(const float4*)&kw_c[rb_];
  };

  auto step = [&](Slot& s, int t) {
    float e0 = tanh_fast(qw + s.kw.x);
    float e1 = tanh_fast(qw + s.kw.y);
    float e2 = tanh_fast(qw + s.kw.z);
    float e3 = tanh_fast(qw + s.kw.w);
    float q0 = __expf(e0), q1 = __expf(e1), q2 = __expf(e2), q3 = __expf(e3);
    float inv = __builtin_amdgcn_rcpf(q0 + q1 + q2 + q3);
    float4 K0 = {b2f(s.k0.x), b2f(s.k0.y), b2f(s.k0.z), b2f(s.k0.w)};
    float4 K1 = {b2f(s.k1.x), b2f(s.k1.y), b2f(s.k1.z), b2f(s.k1.w)};
    float4 K2 = {b2f(s.k2.x), b2f(s.k2.y), b2f(s.k2.z), b2f(s.k2.w)};
    float4 K3 = {b2f(s.k3.x), b2f(s.k3.y), b2f(s.k3.z), b2f(s.k3.w)};
    float4 X  = {b2f(s.x.x) + cbv.x, b2f(s.x.y) + cbv.y,
                 b2f(s.x.z) + cbv.z, b2f(s.x.w) + cbv.w};
    float4 a;
    a.x = fmaf(q0, K0.x, fmaf(q1, K1.x, fmaf(q2, K2.x, q3 * K3.x)));
    a.y = fmaf(q0, K0.y, fmaf(q1, K1.y, fmaf(q2, K2.y, q3 * K3.y)));
    a.z = fmaf(q0, K0.z, fmaf(q1, K1.z, fmaf(q2, K2.z, q3 * K3.z)));
    a.w = fmaf(q0, K0.w, fmaf(q1, K1.w, fmaf(q2, K2.w, q3 * K3.w)));
    float4 u;
    u.x = fmaf(a.x, inv, X.x); u.y = fmaf(a.y, inv, X.y);
    u.z = fmaf(a.z, inv, X.z); u.w = fmaf(a.w, inv, X.w);
    float4 r;
    r.x = fmaxf(u.x, 0.f); r.y = fmaxf(u.y, 0.f);
    r.z = fmaxf(u.z, 0.f); r.w = fmaxf(u.w, 0.f);
    float d = fmaf(r.x, v2v.x, fmaf(r.y, v2v.y, fmaf(r.z, v2v.z, r.w * v2v.w)));
    qw = wave_reduce_sum(d) + c2;
    if (t0 + t == SS - 1)
      *(float4*)&relu_u[(size_t)(b * 4 + i) * 256 + l * 4] = r;
  };

  Slot s0, s1, s2, s3;
  load(s0, 0); load(s1, 1); load(s2, 2); load(s3, 3);
  for (int t = 0; t < n; t += 4) {
    int nt;
    step(s0, t);     nt = t + 4; load(s0, nt < n ? nt : n - 1);
    step(s1, t + 1); nt = t + 5; load(s1, nt < n ? nt : n - 1);
    step(s2, t + 2); nt = t + 6; load(s2, nt < n ? nt : n - 1);
    step(s3, t + 3); nt = t + 7; load(s3, nt < n ? nt : n - 1);
  }
  if (l == 0) ws[768 + b * 4 + i] = qw;
}

// ---------------------------------------------------------------------------
// Fused: blocks [0,64) = seq chunk (prev buffer), blocks [64,..) = precompute
// ---------------------------------------------------------------------------
__global__ __launch_bounds__(256, 2) void fused_kernel(
    const float* __restrict__ x, const unsigned short* __restrict__ wpack,
    const float* __restrict__ bk, const float* __restrict__ b1,
    const float* __restrict__ w_mlp,
    float* kwB, unsigned short* xw1B, unsigned short* kpwB, int t0_pre,
    const float* kwA, const unsigned short* xw1A, const unsigned short* kpwA,
    int t0_seq, int n_seq,
    float* __restrict__ ws, float* __restrict__ relu_u)
{
  __shared__ __align__(16) char smem[2048 + 2 * 64 * LDH * 2];
  if (blockIdx.x < 64) {
    if (n_seq > 0) seq_block(xw1A, kpwA, kwA, ws, relu_u, t0_seq, n_seq);
    return;
  }
  precompute_block(blockIdx.x - 64, x, wpack, bk, b1, w_mlp,
                   kwB, xw1B, kpwB, t0_pre, smem);
}

// ---------------------------------------------------------------------------
__global__ __launch_bounds__(256) void final_hidden_kernel(
    const float* __restrict__ relu_u, const float* __restrict__ W2,
    const float* __restrict__ b2, float* __restrict__ out)
{
  __shared__ float rs[256];
  int row = blockIdx.x;
  int tid = threadIdx.x;
  rs[tid] = relu_u[(size_t)row * 256 + tid];
  __syncthreads();
  float acc = b2[tid];
  for (int k = 0; k < 256; ++k) acc = fmaf(rs[k], W2[k * 256 + tid], acc);
  out[192 + (size_t)row * 256 + tid] = acc;
}

__global__ __launch_bounds__(256) void final_logits_kernel(
    const float* __restrict__ hf, const float* __restrict__ Wo,
    const float* __restrict__ bo, float* __restrict__ outp)
{
  __shared__ float r0[256], r1[256], r2[256];
  int b = blockIdx.x;
  int tid = threadIdx.x;
  float a0 = 0.f, a1 = 0.f, a2 = 0.f;
  for (int k = tid; k < 1024; k += 256) {
    float h = hf[(size_t)b * 1024 + k];
    a0 = fmaf(h, Wo[k * 3 + 0], a0);
    a1 = fmaf(h, Wo[k * 3 + 1], a1);
    a2 = fmaf(h, Wo[k * 3 + 2], a2);
  }
  r0[tid] = a0; r1[tid] = a1; r2[tid] = a2;
  __syncthreads();
  for (int s = 128; s; s >>= 1) {
    if (tid < s) { r0[tid] += r0[tid + s]; r1[tid] += r1[tid + s]; r2[tid] += r2[tid + s]; }
    __syncthreads();
  }
  if (tid == 0) {
    float l0 = r0[0] + bo[0], l1 = r1[0] + bo[1], l2 = r2[0] + bo[2];
    float m = fmaxf(l0, fmaxf(l1, l2));
    float lse = m + logf(expf(l0 - m) + expf(l1 - m) + expf(l2 - m));
    outp[b * 3 + 0] = l0 - lse;
    outp[b * 3 + 1] = l1 - lse;
    outp[b * 3 + 2] = l2 - lse;
  }
}

// ---------------------------------------------------------------------------
extern "C" void kernel_launch(void* const* d_in, const int* in_sizes, int n_in,
                              void* d_out, int out_size, void* d_ws, size_t ws_size,
                              hipStream_t stream)
{
  const float* x     = (const float*)d_in[0];
  const float* Wk    = (const float*)d_in[1];
  const float* bk    = (const float*)d_in[2];
  const float* Wq    = (const float*)d_in[3];
  const float* bq    = (const float*)d_in[4];
  const float* w_mlp = (const float*)d_in[5];
  const float* Wproj = (const float*)d_in[6];
  const float* bproj = (const float*)d_in[7];
  const float* W1    = (const float*)d_in[8];
  const float* b1    = (const float*)d_in[9];
  const float* W2    = (const float*)d_in[10];
  const float* b2    = (const float*)d_in[11];
  const float* Wo    = (const float*)d_in[12];
  const float* bo    = (const float*)d_in[13];
  float* out = (float*)d_out;
  float* ws  = (float*)d_ws;

  float* ru = ws + 1024;
  unsigned short* wpack = (unsigned short*)(ws + 66560);
  const size_t OFF_CH = 66560 + 131072;              // 197632 floats
  const long per_t = 256 + 65536;                    // floats per timestep (kw fp32 + 2 bf16 tiles)

  long ws_floats = (long)(ws_size / 4);
  long avail = ws_floats - (long)OFF_CH;

  int Tc = 128;
  while (Tc > 0 && 2L * Tc * per_t > avail) Tc -= 16;
  bool pipelined = (Tc >= 16);
  if (!pipelined) {
    Tc = 128;
    while (Tc > 16 && (long)Tc * per_t > avail) Tc -= 16;
  }

  float* bufA = ws + OFF_CH;
  float* bufB = pipelined ? bufA + (size_t)Tc * per_t : bufA;

  auto kw_of  = [&](float* base) { return base; };
  auto xw_of  = [&](float* base) { return (unsigned short*)(base + (size_t)Tc * 256); };
  auto kpw_of = [&](float* base) { return (unsigned short*)(base + (size_t)Tc * 256) + (size_t)Tc * 65536; };

  init_kernel<<<1025, 256, 0, stream>>>(Wk, Wproj, W1, Wq, bq, w_mlp, bproj, W2, b2,
                                        ws, wpack);

  int C = (SS + Tc - 1) / Tc;

  if (pipelined) {
    for (int r = 0; r <= C; ++r) {
      bool hasPre = (r < C);
      bool hasSeq = (r >= 1);
      int t0p = r * Tc;
      int np  = hasPre ? ((SS - t0p) < Tc ? (SS - t0p) : Tc) : 0;
      int t0s = (r - 1) * Tc;
      int ns  = hasSeq ? ((SS - t0s) < Tc ? (SS - t0s) : Tc) : 0;
      float* pB = ((r & 1) ? bufB : bufA);
      float* pA = (((r - 1) & 1) ? bufB : bufA);
      int grid = 64 + (hasPre ? 64 * (np / 16) : 0);
      fused_kernel<<<grid, 256, 0, stream>>>(
          x, wpack, bk, b1, w_mlp,
          kw_of(pB), xw_of(pB), kpw_of(pB), t0p,
          kw_of(pA), xw_of(pA), kpw_of(pA), t0s, ns,
          ws, ru);
    }
  } else {
    for (int c = 0; c < C; ++c) {
      int t0 = c * Tc;
      int n = (SS - t0) < Tc ? (SS - t0) : Tc;
      fused_kernel<<<64 + 64 * (n / 16), 256, 0, stream>>>(
          x, wpack, bk, b1, w_mlp,
          kw_of(bufA), xw_of(bufA), kpw_of(bufA), t0,
          kw_of(bufA), xw_of(bufA), kpw_of(bufA), 0, 0,
          ws, ru);
      fused_kernel<<<64, 256, 0, stream>>>(
          x, wpack, bk, b1, w_mlp,
          kw_of(bufA), xw_of(bufA), kpw_of(bufA), t0,
          kw_of(bufA), xw_of(bufA), kpw_of(bufA), t0, n,
          ws, ru);
    }
  }

  final_hidden_kernel<<<BB * NHH, 256, 0, stream>>>(ru, W2, b2, out);
  final_logits_kernel<<<BB, 256, 0, stream>>>(out + 192, Wo, bo, out);
}